// Round 3
// baseline (142.634 us; speedup 1.0000x reference)
//
#include <hip/hip_runtime.h>
#include <hip/hip_bf16.h>

#define NC 24
constexpr int B  = 32;
constexpr int H4 = 128, W4 = 128, HW4 = H4 * W4;   // 16384
constexpr int H5 = 64,  W5 = 64,  HW5 = H5 * W5;   // 4096
constexpr int T4 = 200, T5 = 100;
constexpr int N4 = B * T4, N5 = B * T5;
constexpr int C  = NC + 1;                          // 25
constexpr int NBLK = 2 * B;                         // 64: blocks 0..31 = p4, 32..63 = p5

__device__ __forceinline__ float softplus_abs(float x) { return log1pf(expf(-fabsf(x))); }

// One block per (scale, batch). Phase 1: per-target losses + LDS obj-mask dedup.
// Phase 2: masked negative-obj BCE over this batch's grid + popcount of mask.
// part[bk*8 + {0..4}] = {lb, lo_pos, lc, negloss, pos_count}
__global__ __launch_bounds__(256) void det_fused(
    const float* __restrict__ cls4, const float* __restrict__ reg4,
    const float* __restrict__ tgt4, const float* __restrict__ cls5,
    const float* __restrict__ reg5, const float* __restrict__ tgt5,
    float* __restrict__ part) {
    const int bk   = blockIdx.x;
    const bool isP4 = bk < B;
    const int b    = isP4 ? bk : bk - B;
    const int W    = isP4 ? W4 : W5;
    const int H    = isP4 ? H4 : H5;
    const int HW   = isP4 ? HW4 : HW5;
    const int T    = isP4 ? T4 : T5;
    const float* cls = isP4 ? cls4 : cls5;
    const float* reg = isP4 ? reg4 : reg5;
    const float* tgt = isP4 ? tgt4 : tgt5;
    const int nwords = HW >> 5;

    __shared__ unsigned int mask[HW4 >> 5];   // 512 words (p4); p5 uses first 128
    __shared__ float red[4][8];

    for (int k = threadIdx.x; k < nwords; k += 256) mask[k] = 0u;
    __syncthreads();

    const float* clsb = cls + (size_t)b * C * HW;   // obj channel base; +c*HW for cls c-1
    const float* regb = reg + (size_t)b * 4 * HW;

    float lb = 0.f, lo = 0.f, lc = 0.f;
    for (int t = threadIdx.x; t < T; t += 256) {
        const float* tp = tgt + ((size_t)b * T + t) * 6;
        float f0 = tp[0], f1 = tp[1], f2 = tp[2], f3 = tp[3], f4 = tp[4];
        int   tcls = (int)f0;
        float tx = f1 * (float)W, ty = f2 * (float)H;
        float tw = f3 * (float)W, th = f4 * (float)H;
        int gx = min(max((int)tx, 0), W - 1);
        int gy = min(max((int)ty, 0), H - 1);
        int cell = gy * W + gx;

        // bbox smooth-L1 (mean over 4 coords)
        float r0 = regb[cell];
        float r1 = regb[cell + HW];
        float r2 = regb[cell + 2 * HW];
        float r3 = regb[cell + 3 * HW];
        float px = fminf(fmaxf((float)gx + r0, 0.f), (float)W);
        float py = fminf(fmaxf((float)gy + r1, 0.f), (float)H);
        float pw = fminf(fmaxf(expf(r2), 1.f), (float)W) * 0.1f;
        float ph = fminf(fmaxf(expf(r3), 1.f), (float)H) * 0.1f;
        float s = 0.f, d, ad;
        d = (px - pw * 0.5f) - (tx - tw * 0.5f); ad = fabsf(d); s += (ad < 1.f) ? 0.5f * d * d : ad - 0.5f;
        d = (py - ph * 0.5f) - (ty - th * 0.5f); ad = fabsf(d); s += (ad < 1.f) ? 0.5f * d * d : ad - 0.5f;
        d = (px + pw * 0.5f) - (tx + tw * 0.5f); ad = fabsf(d); s += (ad < 1.f) ? 0.5f * d * d : ad - 0.5f;
        d = (py + ph * 0.5f) - (ty + th * 0.5f); ad = fabsf(d); s += (ad < 1.f) ? 0.5f * d * d : ad - 0.5f;
        lb += s * 0.25f;

        // positive objectness BCE (z=1)
        float obj = clsb[cell];
        lo += fmaxf(obj, 0.f) - obj + softplus_abs(obj);

        // focal classification loss (mean over NC)
        float fs = 0.f;
        #pragma unroll
        for (int c = 0; c < NC; c++) {
            float x = clsb[(c + 1) * HW + cell];
            float z = (tcls == c && tcls < NC) ? 1.f : 0.f;
            float bce = fmaxf(x, 0.f) - x * z + softplus_abs(x);
            float p  = 1.f / (1.f + expf(-x));
            float pt = p * z + (1.f - p) * (1.f - z);
            float om = 1.f - pt;
            fs += 0.25f * om * om * bce;
        }
        lc += fs * (1.f / (float)NC);

        atomicOr(&mask[cell >> 5], 1u << (cell & 31));
    }
    __syncthreads();   // mask complete for this batch

    // Phase 2: negative-obj BCE over this batch's grid, float4 + mask nibble
    float nl = 0.f;
    int pos = 0;
    const int nv = HW >> 2;
    for (int v = threadIdx.x; v < nv; v += 256) {
        int i = v << 2;
        const float4 x = *(const float4*)(clsb + i);
        unsigned int bits = (mask[i >> 5] >> (unsigned)(i & 31)) & 0xFu;
        if (!(bits & 1u)) nl += fmaxf(x.x, 0.f) + softplus_abs(x.x);
        if (!(bits & 2u)) nl += fmaxf(x.y, 0.f) + softplus_abs(x.y);
        if (!(bits & 4u)) nl += fmaxf(x.z, 0.f) + softplus_abs(x.z);
        if (!(bits & 8u)) nl += fmaxf(x.w, 0.f) + softplus_abs(x.w);
    }
    for (int k = threadIdx.x; k < nwords; k += 256) pos += __popc(mask[k]);
    float posf = (float)pos;

    // block reduction of 5 values
    #pragma unroll
    for (int o = 32; o > 0; o >>= 1) {
        lb   += __shfl_down(lb, o);
        lo   += __shfl_down(lo, o);
        lc   += __shfl_down(lc, o);
        nl   += __shfl_down(nl, o);
        posf += __shfl_down(posf, o);
    }
    int wv = threadIdx.x >> 6, ln = threadIdx.x & 63;
    if (ln == 0) {
        red[wv][0] = lb; red[wv][1] = lo; red[wv][2] = lc;
        red[wv][3] = nl; red[wv][4] = posf;
    }
    __syncthreads();
    if (threadIdx.x < 5) {
        part[bk * 8 + threadIdx.x] =
            red[0][threadIdx.x] + red[1][threadIdx.x] +
            red[2][threadIdx.x] + red[3][threadIdx.x];
    }
}

// One wave: reduce 64 partial records, apply normalizations, write 4 outputs.
__global__ __launch_bounds__(64) void det_final(
    const float* __restrict__ part, float* __restrict__ out) {
    int t = threadIdx.x;   // t in [0,64) — exactly one partial record each
    bool p4 = t < B;
    float lb = part[t * 8 + 0];
    float lo = part[t * 8 + 1];
    float lc = part[t * 8 + 2];
    float nlv  = part[t * 8 + 3];
    float posv = part[t * 8 + 4];
    float nl4 = p4 ? nlv : 0.f,  nl5 = p4 ? 0.f : nlv;
    float ps4 = p4 ? posv : 0.f, ps5 = p4 ? 0.f : posv;
    #pragma unroll
    for (int o = 32; o > 0; o >>= 1) {
        lb  += __shfl_down(lb, o);
        lo  += __shfl_down(lo, o);
        lc  += __shfl_down(lc, o);
        nl4 += __shfl_down(nl4, o);
        nl5 += __shfl_down(nl5, o);
        ps4 += __shfl_down(ps4, o);
        ps5 += __shfl_down(ps5, o);
    }
    if (t == 0) {
        float n = (float)(N4 + N5);
        float lbn = lb / n;
        float lcn = lc / n;
        float neg4 = (float)(B * HW4) - ps4;
        float neg5 = (float)(B * HW5) - ps5;
        float lo_sum = lo + nl4 / neg4 * 0.5f + nl5 / neg5 * 0.5f;
        float lon = lo_sum / ((float)(B * HW4 + B * HW5) + 1e-8f);
        out[0] = lbn + lon + lcn;
        out[1] = lbn;
        out[2] = lon;
        out[3] = lcn;
    }
}

extern "C" void kernel_launch(void* const* d_in, const int* in_sizes, int n_in,
                              void* d_out, int out_size, void* d_ws, size_t ws_size,
                              hipStream_t stream) {
    const float* cls4 = (const float*)d_in[0];
    const float* reg4 = (const float*)d_in[1];
    const float* cls5 = (const float*)d_in[2];
    const float* reg5 = (const float*)d_in[3];
    const float* tgt4 = (const float*)d_in[4];
    const float* tgt5 = (const float*)d_in[5];
    float* out  = (float*)d_out;
    float* part = (float*)d_ws;   // 64 records * 8 floats; fully written each call

    det_fused<<<NBLK, 256, 0, stream>>>(cls4, reg4, tgt4, cls5, reg5, tgt5, part);
    det_final<<<1, 64, 0, stream>>>(part, out);
}

// Round 4
// 125.627 us; speedup vs baseline: 1.1354x; 1.1354x over previous
//
#include <hip/hip_runtime.h>
#include <hip/hip_bf16.h>

#define NC 24
constexpr int B  = 32;
constexpr int H4 = 128, W4 = 128, HW4 = H4 * W4;   // 16384
constexpr int H5 = 64,  W5 = 64,  HW5 = H5 * W5;   // 4096
constexpr int T4 = 200, T5 = 100;
constexpr int N4 = B * T4, N5 = B * T5;            // 6400, 3200
constexpr int C  = NC + 1;                          // 25

constexpr int TPB = 256;
constexpr int TGT_PER_BLK = TPB / 32;               // 8 targets per block
constexpr int BLK4 = N4 / TGT_PER_BLK;              // 800
constexpr int BLK5 = N5 / TGT_PER_BLK;              // 400
constexpr int DBLK = 40;                            // dense-sweep blocks
constexpr int NBLK = BLK4 + BLK5 + DBLK;            // 1240
constexpr int NV4 = B * HW4 / 4;                    // 131072 float4
constexpr int NV5 = B * HW5 / 4;                    // 32768 float4

// ws layout
constexpr size_t PART_OFF  = 0;                     // 1240 * 8 floats = 39680 B
constexpr size_t MASK4_OFF = 65536;                 // 65536 B
constexpr size_t MASK5_OFF = MASK4_OFF + 65536;     // 16384 B
constexpr size_t MASK_BYTES = 65536 + 16384;

__device__ __forceinline__ float softplus_abs(float x) { return log1pf(expf(-fabsf(x))); }
__device__ __forceinline__ float bce_neg(float x) { return fmaxf(x, 0.f) + softplus_abs(x); }

// part[k*8+..]: 0=lb 1=lo_pos 2=lc 3=sub(scale of block) 4=cnt 5=all4 6=all5
__global__ __launch_bounds__(256) void det_main(
    const float* __restrict__ cls4, const float* __restrict__ reg4,
    const float* __restrict__ tgt4, const float* __restrict__ cls5,
    const float* __restrict__ reg5, const float* __restrict__ tgt5,
    unsigned int* __restrict__ mask4, unsigned int* __restrict__ mask5,
    float* __restrict__ part) {
    const int bk = blockIdx.x;
    float lb = 0.f, lo = 0.f, lc = 0.f, sub = 0.f, cnt = 0.f, all4 = 0.f, all5 = 0.f;

    if (bk < BLK4 + BLK5) {
        // ---- target blocks: 32 lanes cooperate on one target ----
        const bool isP4 = bk < BLK4;
        const int W  = isP4 ? W4 : W5;
        const int H  = isP4 ? H4 : H5;
        const int HW = isP4 ? HW4 : HW5;
        const float* cls = isP4 ? cls4 : cls5;
        const float* reg = isP4 ? reg4 : reg5;
        const float* tgt = isP4 ? tgt4 : tgt5;
        unsigned int* mask = isP4 ? mask4 : mask5;

        const int trel = (isP4 ? bk : bk - BLK4) * TGT_PER_BLK + (threadIdx.x >> 5);
        const int c = threadIdx.x & 31;
        const int b = isP4 ? (trel / T4) : (trel / T5);

        const float* tp = tgt + (size_t)trel * 6;
        const int   tcls = (int)tp[0];
        const float tx = tp[1] * (float)W;
        const float ty = tp[2] * (float)H;
        const int gx = min(max((int)tx, 0), W - 1);
        const int gy = min(max((int)ty, 0), H - 1);
        const int cell = gy * W + gx;
        const float* clsb = cls + (size_t)b * C * HW;

        if (c == 0) {
            // positive objectness BCE + first-setter dedup of the negative mask
            float obj = clsb[cell];
            lo = fmaxf(obj, 0.f) - obj + softplus_abs(obj);
            unsigned int mcell = (unsigned int)(b * HW + cell);
            unsigned int bit = 1u << (mcell & 31);
            unsigned int old = atomicOr(&mask[mcell >> 5], bit);
            if (!(old & bit)) {              // unique owner of this positive cell
                sub = bce_neg(obj);
                cnt = 1.f;
            }
        } else if (c <= NC) {
            // focal classification term for class c-1
            float x = clsb[(size_t)c * HW + cell];
            float z = (tcls == (c - 1) && tcls < NC) ? 1.f : 0.f;
            float bce = fmaxf(x, 0.f) - x * z + softplus_abs(x);
            float p  = 1.f / (1.f + expf(-x));
            float pt = p * z + (1.f - p) * (1.f - z);
            float om = 1.f - pt;
            lc = 0.25f * om * om * bce * (1.f / (float)NC);
        } else if (c == 25) {
            // bbox smooth-L1 (mean over 4 coords)
            const float tw = tp[3] * (float)W;
            const float th = tp[4] * (float)H;
            const float* regb = reg + (size_t)b * 4 * HW + cell;
            float r0 = regb[0];
            float r1 = regb[HW];
            float r2 = regb[2 * HW];
            float r3 = regb[3 * HW];
            float px = fminf(fmaxf((float)gx + r0, 0.f), (float)W);
            float py = fminf(fmaxf((float)gy + r1, 0.f), (float)H);
            float pw = fminf(fmaxf(expf(r2), 1.f), (float)W) * 0.1f;
            float ph = fminf(fmaxf(expf(r3), 1.f), (float)H) * 0.1f;
            float s = 0.f, d, ad;
            d = (px - pw * 0.5f) - (tx - tw * 0.5f); ad = fabsf(d); s += (ad < 1.f) ? 0.5f * d * d : ad - 0.5f;
            d = (py - ph * 0.5f) - (ty - th * 0.5f); ad = fabsf(d); s += (ad < 1.f) ? 0.5f * d * d : ad - 0.5f;
            d = (px + pw * 0.5f) - (tx + tw * 0.5f); ad = fabsf(d); s += (ad < 1.f) ? 0.5f * d * d : ad - 0.5f;
            d = (py + ph * 0.5f) - (ty + th * 0.5f); ad = fabsf(d); s += (ad < 1.f) ? 0.5f * d * d : ad - 0.5f;
            lb = s * 0.25f;
        }
    } else {
        // ---- dense blocks: unmasked bce_neg sum over both obj channels ----
        const int d = bk - (BLK4 + BLK5);
        for (int v = d * TPB + threadIdx.x; v < NV4; v += DBLK * TPB) {
            int i = v << 2;
            int b = i >> 14, rem = i & (HW4 - 1);
            const float4 x = *(const float4*)(cls4 + (size_t)b * C * HW4 + rem);
            all4 += bce_neg(x.x) + bce_neg(x.y) + bce_neg(x.z) + bce_neg(x.w);
        }
        for (int v = d * TPB + threadIdx.x; v < NV5; v += DBLK * TPB) {
            int i = v << 2;
            int b = i >> 12, rem = i & (HW5 - 1);
            const float4 x = *(const float4*)(cls5 + (size_t)b * C * HW5 + rem);
            all5 += bce_neg(x.x) + bce_neg(x.y) + bce_neg(x.z) + bce_neg(x.w);
        }
    }

    // block reduction of 7 values
    #pragma unroll
    for (int o = 32; o > 0; o >>= 1) {
        lb   += __shfl_down(lb, o);
        lo   += __shfl_down(lo, o);
        lc   += __shfl_down(lc, o);
        sub  += __shfl_down(sub, o);
        cnt  += __shfl_down(cnt, o);
        all4 += __shfl_down(all4, o);
        all5 += __shfl_down(all5, o);
    }
    __shared__ float red[4][8];
    int wv = threadIdx.x >> 6, ln = threadIdx.x & 63;
    if (ln == 0) {
        red[wv][0] = lb;  red[wv][1] = lo;   red[wv][2] = lc;  red[wv][3] = sub;
        red[wv][4] = cnt; red[wv][5] = all4; red[wv][6] = all5;
    }
    __syncthreads();
    if (threadIdx.x < 7) {
        part[bk * 8 + threadIdx.x] =
            red[0][threadIdx.x] + red[1][threadIdx.x] +
            red[2][threadIdx.x] + red[3][threadIdx.x];
    }
}

__global__ __launch_bounds__(256) void det_final(
    const float* __restrict__ part, float* __restrict__ out) {
    float lb = 0.f, lo = 0.f, lc = 0.f;
    float s4 = 0.f, c4 = 0.f, s5 = 0.f, c5 = 0.f, a4 = 0.f, a5 = 0.f;
    for (int k = threadIdx.x; k < NBLK; k += 256) {
        const float* p = part + (size_t)k * 8;
        lb += p[0]; lo += p[1]; lc += p[2];
        a4 += p[5]; a5 += p[6];
        if (k < BLK4)             { s4 += p[3]; c4 += p[4]; }
        else if (k < BLK4 + BLK5) { s5 += p[3]; c5 += p[4]; }
    }
    #pragma unroll
    for (int o = 32; o > 0; o >>= 1) {
        lb += __shfl_down(lb, o); lo += __shfl_down(lo, o); lc += __shfl_down(lc, o);
        s4 += __shfl_down(s4, o); c4 += __shfl_down(c4, o);
        s5 += __shfl_down(s5, o); c5 += __shfl_down(c5, o);
        a4 += __shfl_down(a4, o); a5 += __shfl_down(a5, o);
    }
    __shared__ float red[4][12];
    int wv = threadIdx.x >> 6, ln = threadIdx.x & 63;
    if (ln == 0) {
        red[wv][0] = lb; red[wv][1] = lo; red[wv][2] = lc;
        red[wv][3] = s4; red[wv][4] = c4; red[wv][5] = s5;
        red[wv][6] = c5; red[wv][7] = a4; red[wv][8] = a5;
    }
    __syncthreads();
    if (threadIdx.x == 0) {
        float v[9];
        #pragma unroll
        for (int j = 0; j < 9; j++)
            v[j] = red[0][j] + red[1][j] + red[2][j] + red[3][j];
        float n = (float)(N4 + N5);
        float lbn = v[0] / n;
        float lcn = v[2] / n;
        float nl4 = v[7] - v[3];                 // all4 - sub4
        float nl5 = v[8] - v[5];
        float neg4 = (float)(B * HW4) - v[4];
        float neg5 = (float)(B * HW5) - v[6];
        float lo_sum = v[1] + nl4 / neg4 * 0.5f + nl5 / neg5 * 0.5f;
        float lon = lo_sum / ((float)(B * HW4 + B * HW5) + 1e-8f);
        out[0] = lbn + lon + lcn;
        out[1] = lbn;
        out[2] = lon;
        out[3] = lcn;
    }
}

extern "C" void kernel_launch(void* const* d_in, const int* in_sizes, int n_in,
                              void* d_out, int out_size, void* d_ws, size_t ws_size,
                              hipStream_t stream) {
    const float* cls4 = (const float*)d_in[0];
    const float* reg4 = (const float*)d_in[1];
    const float* cls5 = (const float*)d_in[2];
    const float* reg5 = (const float*)d_in[3];
    const float* tgt4 = (const float*)d_in[4];
    const float* tgt5 = (const float*)d_in[5];
    float* out = (float*)d_out;

    float* part = (float*)((char*)d_ws + PART_OFF);
    unsigned int* mask4 = (unsigned int*)((char*)d_ws + MASK4_OFF);
    unsigned int* mask5 = (unsigned int*)((char*)d_ws + MASK5_OFF);

    hipMemsetAsync((char*)d_ws + MASK4_OFF, 0, MASK_BYTES, stream);

    det_main<<<NBLK, TPB, 0, stream>>>(cls4, reg4, tgt4, cls5, reg5, tgt5,
                                       mask4, mask5, part);
    det_final<<<1, 256, 0, stream>>>(part, out);
}